// Round 13
// baseline (275.450 us; speedup 1.0000x reference)
//
#include <hip/hip_runtime.h>
#include <hip/hip_fp16.h>

// GCN: N=100000, E=1600000, F=H=128, D=64, O=1.
// R13: R12 + schedule restructure:
//   - fixed-stride buckets (STRIDE=2560, 11-sigma headroom) -> scanK2 deleted,
//     bucket_csr emits rowbeg/rowend (strided CSR)
//   - mega1 = histH || prep_w ; mega3 = scatterH || gemm1  (overlap)
//   - CHUNK 16384. 8 launches total.
// Agg gather held at pattern roofline (~3.2-3.6 TB/s L2-miss fill).

#define CHUNK 16384
#define STRIDE 2560
#define ASTR 136   // LDS stride in halves

using f16x8 = __attribute__((ext_vector_type(8))) _Float16;
using f32x4 = __attribute__((ext_vector_type(4))) float;

// ====== device bodies ======
__device__ __forceinline__ void hist_body(const int* __restrict__ dst,
                                          int* __restrict__ hist,
                                          int E, int NBKT, int NB, int blk) {
    __shared__ int bins[1024];
    for (int i = threadIdx.x; i < NBKT; i += 256) bins[i] = 0;
    __syncthreads();
    int beg = blk * CHUNK, end = min(E, beg + CHUNK);
    for (int e = beg + threadIdx.x; e < end; e += 256)
        atomicAdd(&bins[dst[e] >> 7], 1);
    __syncthreads();
    for (int i = threadIdx.x; i < NBKT; i += 256)
        hist[i * NB + blk] = bins[i];
}

__device__ __forceinline__ void prep_body(int which,
                                          const float* __restrict__ W1,
                                          const float* __restrict__ Wh,
                                          const float* __restrict__ W2,
                                          const float* __restrict__ b2,
                                          const float* __restrict__ Wo,
                                          const float* __restrict__ bo,
                                          __half* __restrict__ Wt1,
                                          __half* __restrict__ WtH,
                                          float* __restrict__ w3,
                                          float* __restrict__ c3) {
    const float* W = which ? Wh : W1;
    __half* Wt = which ? WtH : Wt1;
    for (int i = threadIdx.x; i < 16384; i += 256) {
        int c = i >> 7, k = i & 127;
        Wt[c * 128 + k] = __float2half(W[k * 128 + c]);
    }
    if (which == 0 && threadIdx.x < 128) {
        int j = threadIdx.x;
        float s = 0.f;
        for (int d = 0; d < 64; ++d) s += W2[j * 64 + d] * Wo[d];
        w3[j] = s;
        if (j == 0) {
            float c = 0.f;
            for (int d = 0; d < 64; ++d) c += b2[d] * Wo[d];
            *c3 = c + bo[0];
        }
    }
}

__device__ __forceinline__ void scatter_body(const int* __restrict__ src,
                                             const int* __restrict__ dst,
                                             const int* __restrict__ hist,
                                             int* __restrict__ tmp,
                                             int E, int NBKT, int NB, int blk) {
    __shared__ int offs[1024];
    for (int i = threadIdx.x; i < NBKT; i += 256)
        offs[i] = hist[i * NB + blk] + i * STRIDE;
    __syncthreads();
    int beg = blk * CHUNK, end = min(E, beg + CHUNK);
    for (int e = beg + threadIdx.x; e < end; e += 256) {
        int d = dst[e];
        int bkt = d >> 7;
        int pos = atomicAdd(&offs[bkt], 1);
        if (pos < (bkt + 1) * STRIDE)           // 11-sigma guard, never fires
            tmp[pos] = ((d & 127) << 17) | src[e];
    }
}

// gemm body: Ch[n,128] = half(A[n,128] @ W), W^T fp16 table. No dinv.
template<typename AT>
__device__ __forceinline__ void gemm_body(const AT* __restrict__ A,
                                          const __half* __restrict__ Wt,
                                          __half* __restrict__ Ch, int n, int blk) {
    __shared__ _Float16 Al[64 * ASTR];
    __shared__ _Float16 Wl[128 * ASTR];
    const int tid = threadIdx.x;
    const int row0 = blk * 64;

#pragma unroll
    for (int i = 0; i < 8; ++i) {
        int idx = tid + 256 * i;
        int c = idx >> 4, q = idx & 15;
        uint4 v = *(const uint4*)(Wt + c * 128 + q * 8);
        *(uint4*)(&Wl[c * ASTR + q * 8]) = v;
    }
#pragma unroll
    for (int i = 0; i < 4; ++i) {
        int idx = tid + 256 * i;
        int r = idx >> 4, q = idx & 15;
        int row = row0 + r;
        uint4 u;
        if constexpr (sizeof(AT) == 2) {
            u = (row < n) ? *(const uint4*)((const __half*)A + (size_t)row * 128 + q * 8)
                          : make_uint4(0u, 0u, 0u, 0u);
        } else {
            if (row < n) {
                const float* ap = (const float*)A + (size_t)row * 128 + q * 8;
                float4 v0 = *(const float4*)ap;
                float4 v1 = *(const float4*)(ap + 4);
                __half2 p0 = __floats2half2_rn(v0.x, v0.y);
                __half2 p1 = __floats2half2_rn(v0.z, v0.w);
                __half2 p2 = __floats2half2_rn(v1.x, v1.y);
                __half2 p3 = __floats2half2_rn(v1.z, v1.w);
                u.x = *(unsigned*)&p0; u.y = *(unsigned*)&p1;
                u.z = *(unsigned*)&p2; u.w = *(unsigned*)&p3;
            } else u = make_uint4(0u, 0u, 0u, 0u);
        }
        *(uint4*)(&Al[r * ASTR + q * 8]) = u;
    }
    __syncthreads();

    const int wave = tid >> 6, lane = tid & 63;
    const int wr = (wave >> 1) * 32;
    const int wc = (wave & 1) * 64;
    const int l = lane & 15, g = lane >> 4;

    f32x4 acc[2][4];
#pragma unroll
    for (int i = 0; i < 2; ++i)
#pragma unroll
        for (int j = 0; j < 4; ++j) acc[i][j] = (f32x4){0.f, 0.f, 0.f, 0.f};

#pragma unroll
    for (int kk = 0; kk < 128; kk += 32) {
        int ko = kk + g * 8;
        f16x8 a0 = *(const f16x8*)(&Al[(wr + l) * ASTR + ko]);
        f16x8 a1 = *(const f16x8*)(&Al[(wr + 16 + l) * ASTR + ko]);
        f16x8 b0 = *(const f16x8*)(&Wl[(wc + l) * ASTR + ko]);
        f16x8 b1 = *(const f16x8*)(&Wl[(wc + 16 + l) * ASTR + ko]);
        f16x8 b2 = *(const f16x8*)(&Wl[(wc + 32 + l) * ASTR + ko]);
        f16x8 b3 = *(const f16x8*)(&Wl[(wc + 48 + l) * ASTR + ko]);
        acc[0][0] = __builtin_amdgcn_mfma_f32_16x16x32_f16(a0, b0, acc[0][0], 0, 0, 0);
        acc[0][1] = __builtin_amdgcn_mfma_f32_16x16x32_f16(a0, b1, acc[0][1], 0, 0, 0);
        acc[0][2] = __builtin_amdgcn_mfma_f32_16x16x32_f16(a0, b2, acc[0][2], 0, 0, 0);
        acc[0][3] = __builtin_amdgcn_mfma_f32_16x16x32_f16(a0, b3, acc[0][3], 0, 0, 0);
        acc[1][0] = __builtin_amdgcn_mfma_f32_16x16x32_f16(a1, b0, acc[1][0], 0, 0, 0);
        acc[1][1] = __builtin_amdgcn_mfma_f32_16x16x32_f16(a1, b1, acc[1][1], 0, 0, 0);
        acc[1][2] = __builtin_amdgcn_mfma_f32_16x16x32_f16(a1, b2, acc[1][2], 0, 0, 0);
        acc[1][3] = __builtin_amdgcn_mfma_f32_16x16x32_f16(a1, b3, acc[1][3], 0, 0, 0);
    }

    // D layout (m89-verified): col = lane&15, row = (lane>>4)*4 + reg
#pragma unroll
    for (int rt = 0; rt < 2; ++rt) {
#pragma unroll
        for (int j = 0; j < 4; ++j) {
            int row = row0 + wr + rt * 16 + g * 4 + j;
            if (row < n) {
#pragma unroll
                for (int ct = 0; ct < 4; ++ct)
                    Ch[(size_t)row * 128 + wc + ct * 16 + l] =
                        __float2half(acc[rt][ct][j]);
            }
        }
    }
}

// ====== fused launches ======
__global__ __launch_bounds__(256) void mega1(const int* __restrict__ dst,
                                             int* __restrict__ hist,
                                             int E, int NBKT, int NB,
                                             const float* __restrict__ W1,
                                             const float* __restrict__ Wh,
                                             const float* __restrict__ W2,
                                             const float* __restrict__ b2,
                                             const float* __restrict__ Wo,
                                             const float* __restrict__ bo,
                                             __half* __restrict__ Wt1,
                                             __half* __restrict__ WtH,
                                             float* __restrict__ w3,
                                             float* __restrict__ c3) {
    if ((int)blockIdx.x < NB)
        hist_body(dst, hist, E, NBKT, NB, blockIdx.x);
    else
        prep_body(blockIdx.x - NB, W1, Wh, W2, b2, Wo, bo, Wt1, WtH, w3, c3);
}

__global__ __launch_bounds__(256) void mega3(const int* __restrict__ src,
                                             const int* __restrict__ dst,
                                             const int* __restrict__ hist,
                                             int* __restrict__ tmp,
                                             int E, int NBKT, int NB,
                                             const float* __restrict__ x,
                                             const __half* __restrict__ Wt1,
                                             __half* __restrict__ g1, int n) {
    if ((int)blockIdx.x < NB)
        scatter_body(src, dst, hist, tmp, E, NBKT, NB, blockIdx.x);
    else
        gemm_body<float>(x, Wt1, g1, n, blockIdx.x - NB);
}

__global__ __launch_bounds__(256) void gemm2_k(const __half* __restrict__ A,
                                               const __half* __restrict__ Wt,
                                               __half* __restrict__ Ch, int n) {
    gemm_body<__half>(A, Wt, Ch, n, blockIdx.x);
}

// ====== CSR build: per-bin wave scan (prefix in place + binsum) ======
__global__ __launch_bounds__(256) void scanA(int* __restrict__ hist, int* __restrict__ binsum,
                                             int NBKT, int NB) {
    int wave = (int)((blockIdx.x * (size_t)blockDim.x + threadIdx.x) >> 6);
    if (wave >= NBKT) return;
    int lane = threadIdx.x & 63;
    int* row = hist + (size_t)wave * NB;
    int running = 0;
    for (int b0 = 0; b0 < NB; b0 += 64) {
        int idx = b0 + lane;
        int v = (idx < NB) ? row[idx] : 0;
        int s = v;
#pragma unroll
        for (int off = 1; off < 64; off <<= 1) {
            int u = __shfl_up(s, off, 64);
            if (lane >= off) s += u;
        }
        if (idx < NB) row[idx] = running + s - v;
        running += __shfl(s, 63, 64);
    }
    if (lane == 0) binsum[wave] = running;
}

// ====== per-bucket CSR compaction: rowbeg/rowend + srcidx + dinv ======
#define EBUF 2688
__global__ __launch_bounds__(256) void bucket_csr(const int* __restrict__ tmp,
                                                  const int* __restrict__ binsum,
                                                  int* __restrict__ rowbeg,
                                                  int* __restrict__ rowend,
                                                  int* __restrict__ srcidx,
                                                  float* __restrict__ dinv,
                                                  int n) {
    __shared__ int cnt[128], sc[128], cnt2[128];
    __shared__ int ebuf[EBUF];
    int b = blockIdx.x;
    int bstart = b * STRIDE;
    int cntE = min(binsum[b], STRIDE);
    if (threadIdx.x < 128) cnt[threadIdx.x] = 0;
    __syncthreads();
    for (int e = threadIdx.x; e < cntE; e += 256) {
        int p = tmp[bstart + e];
        ebuf[e] = p;
        atomicAdd(&cnt[p >> 17], 1);
    }
    __syncthreads();
    if (threadIdx.x < 128) sc[threadIdx.x] = cnt[threadIdx.x];
    __syncthreads();
    for (int off = 1; off < 128; off <<= 1) {
        int u = 0;
        if (threadIdx.x < 128 && threadIdx.x >= off) u = sc[threadIdx.x - off];
        __syncthreads();
        if (threadIdx.x < 128) sc[threadIdx.x] += u;
        __syncthreads();
    }
    if (threadIdx.x < 128) {
        int excl = sc[threadIdx.x] - cnt[threadIdx.x];
        cnt2[threadIdx.x] = excl;
        int id = b * 128 + threadIdx.x;
        if (id < n) {
            rowbeg[id] = bstart + excl;
            rowend[id] = bstart + excl + cnt[threadIdx.x];
            dinv[id] = rsqrtf((float)cnt[threadIdx.x] + 1.0f);
        }
    }
    __syncthreads();
    for (int e = threadIdx.x; e < cntE; e += 256) {
        int p = ebuf[e];
        int pos = bstart + atomicAdd(&cnt2[p >> 17], 1);
        srcidx[pos] = p & 0x1FFFF;
    }
}

// ====== CSR gather: half-wave per node, 2 streams, 4-edge pipeline ======
template<int MODE, int EDGE_DINV>
__global__ __launch_bounds__(256) void agg_csr(const int* __restrict__ rowbeg,
                                               const int* __restrict__ rowend,
                                               const int* __restrict__ srcidx,
                                               const float* __restrict__ dinv,
                                               const __half* __restrict__ Gh,
                                               const float* __restrict__ bias,
                                               const float* __restrict__ w3,
                                               void* __restrict__ outp, int n) {
    int node = (int)((blockIdx.x * (size_t)blockDim.x + threadIdx.x) >> 5);
    if (node >= n) return;
    const int lane = threadIdx.x & 63;
    const int l32 = lane & 31;
    const int strm = l32 >> 4;
    const int l = l32 & 15;
    const int co = l * 8;
    int beg = rowbeg[node], end = rowend[node];
    float di = dinv[node];

    float4 aLo = make_float4(0.f, 0.f, 0.f, 0.f);
    float4 aHi = make_float4(0.f, 0.f, 0.f, 0.f);

#define ACCS(u, s)                                                          \
    {                                                                       \
        float2 f0 = __half22float2(*(const __half2*)&(u).x);                \
        float2 f1 = __half22float2(*(const __half2*)&(u).y);                \
        float2 f2 = __half22float2(*(const __half2*)&(u).z);                \
        float2 f3 = __half22float2(*(const __half2*)&(u).w);                \
        aLo.x = fmaf(f0.x, s, aLo.x); aLo.y = fmaf(f0.y, s, aLo.y);         \
        aLo.z = fmaf(f1.x, s, aLo.z); aLo.w = fmaf(f1.y, s, aLo.w);         \
        aHi.x = fmaf(f2.x, s, aHi.x); aHi.y = fmaf(f2.y, s, aHi.y);         \
        aHi.z = fmaf(f3.x, s, aHi.z); aHi.w = fmaf(f3.y, s, aHi.w);         \
    }

    if (strm == 0) {  // self-loop term
        uint4 u = *(const uint4*)(Gh + (size_t)node * 128 + co);
        float sf = EDGE_DINV ? di : 1.0f;
        ACCS(u, sf);
    }

    int e = beg + strm;
    for (; e + 6 < end; e += 8) {
        int s0 = srcidx[e], s1 = srcidx[e + 2], s2 = srcidx[e + 4], s3 = srcidx[e + 6];
        float d0 = 1.f, d1 = 1.f, d2 = 1.f, d3 = 1.f;
        if (EDGE_DINV) { d0 = dinv[s0]; d1 = dinv[s1]; d2 = dinv[s2]; d3 = dinv[s3]; }
        uint4 u0 = *(const uint4*)(Gh + (size_t)s0 * 128 + co);
        uint4 u1 = *(const uint4*)(Gh + (size_t)s1 * 128 + co);
        uint4 u2 = *(const uint4*)(Gh + (size_t)s2 * 128 + co);
        uint4 u3 = *(const uint4*)(Gh + (size_t)s3 * 128 + co);
        ACCS(u0, d0);
        ACCS(u1, d1);
        ACCS(u2, d2);
        ACCS(u3, d3);
    }
    for (; e < end; e += 2) {
        int s0 = srcidx[e];
        float d0 = EDGE_DINV ? dinv[s0] : 1.0f;
        uint4 u0 = *(const uint4*)(Gh + (size_t)s0 * 128 + co);
        ACCS(u0, d0);
    }
#undef ACCS

    aLo.x += __shfl_xor(aLo.x, 16, 64); aLo.y += __shfl_xor(aLo.y, 16, 64);
    aLo.z += __shfl_xor(aLo.z, 16, 64); aLo.w += __shfl_xor(aLo.w, 16, 64);
    aHi.x += __shfl_xor(aHi.x, 16, 64); aHi.y += __shfl_xor(aHi.y, 16, 64);
    aHi.z += __shfl_xor(aHi.z, 16, 64); aHi.w += __shfl_xor(aHi.w, 16, 64);

    float4 b0 = *(const float4*)(bias + co);
    float4 b1 = *(const float4*)(bias + co + 4);
    float o0 = fmaxf(di * aLo.x + b0.x, 0.f);
    float o1 = fmaxf(di * aLo.y + b0.y, 0.f);
    float o2 = fmaxf(di * aLo.z + b0.z, 0.f);
    float o3 = fmaxf(di * aLo.w + b0.w, 0.f);
    float o4 = fmaxf(di * aHi.x + b1.x, 0.f);
    float o5 = fmaxf(di * aHi.y + b1.y, 0.f);
    float o6 = fmaxf(di * aHi.z + b1.z, 0.f);
    float o7 = fmaxf(di * aHi.w + b1.w, 0.f);

    if constexpr (MODE == 0) {
        if (strm == 0) {
            // h1s = di * h1 (pre-scaled so gemm2 needs no dinv)
            __half2 p0 = __floats2half2_rn(di * o0, di * o1);
            __half2 p1 = __floats2half2_rn(di * o2, di * o3);
            __half2 p2 = __floats2half2_rn(di * o4, di * o5);
            __half2 p3 = __floats2half2_rn(di * o6, di * o7);
            uint4 u;
            u.x = *(unsigned*)&p0; u.y = *(unsigned*)&p1;
            u.z = *(unsigned*)&p2; u.w = *(unsigned*)&p3;
            *(uint4*)((__half*)outp + (size_t)node * 128 + co) = u;
        }
    } else {
        float4 w0 = *(const float4*)(w3 + co);
        float4 w1 = *(const float4*)(w3 + co + 4);
        float v = o0 * w0.x + o1 * w0.y + o2 * w0.z + o3 * w0.w
                + o4 * w1.x + o5 * w1.y + o6 * w1.z + o7 * w1.w;
        v += __shfl_xor(v, 1, 64);
        v += __shfl_xor(v, 2, 64);
        v += __shfl_xor(v, 4, 64);
        v += __shfl_xor(v, 8, 64);
        if (l32 == 0) ((float*)outp)[node] = di * v;
    }
}

// ---- scalar CSR gather for final output ----
__global__ void agg_csr_scalar(const int* __restrict__ rowbeg, const int* __restrict__ rowend,
                               const int* __restrict__ srcidx,
                               const float* __restrict__ dinv, const float* __restrict__ ys,
                               const float* __restrict__ c3, float* __restrict__ out, int n) {
    int i = blockIdx.x * blockDim.x + threadIdx.x;
    if (i >= n) return;
    int beg = rowbeg[i], end = rowend[i];
    float acc = ys[i];
    int e = beg;
    for (; e + 3 < end; e += 4) {
        acc += ys[srcidx[e]] + ys[srcidx[e + 1]] + ys[srcidx[e + 2]] + ys[srcidx[e + 3]];
    }
    for (; e < end; ++e) acc += ys[srcidx[e]];
    out[i] = dinv[i] * acc + c3[0];
}

static inline size_t align4(size_t x) { return (x + 3) & ~(size_t)3; }

extern "C" void kernel_launch(void* const* d_in, const int* in_sizes, int n_in,
                              void* d_out, int out_size, void* d_ws, size_t ws_size,
                              hipStream_t stream) {
    const float* x  = (const float*)d_in[0];
    const int* ei   = (const int*)d_in[1];
    const float* W1 = (const float*)d_in[2];
    const float* b1 = (const float*)d_in[3];
    const float* Wh = (const float*)d_in[4];
    const float* bh = (const float*)d_in[5];
    const float* W2 = (const float*)d_in[6];
    const float* b2 = (const float*)d_in[7];
    const float* Wo = (const float*)d_in[8];
    const float* bo = (const float*)d_in[9];
    float* out = (float*)d_out;

    const int n = in_sizes[0] / 128;
    const int E = in_sizes[1] / 2;
    const int* src = ei;
    const int* dst = ei + E;

    const int NB = (E + CHUNK - 1) / CHUNK;
    const int NBKT = ((n - 1) >> 7) + 1;

    size_t o = 0;
    int* rowbeg = (int*)d_ws + o;        o = align4(o + n);
    int* rowend = (int*)d_ws + o;        o = align4(o + n);
    int* srcidx = (int*)d_ws + o;        o = align4(o + (size_t)NBKT * STRIDE);
    int* tmp    = (int*)d_ws + o;        o = align4(o + (size_t)NBKT * STRIDE);
    int* hist   = (int*)d_ws + o;        o = align4(o + (size_t)NBKT * NB);
    int* binsum = (int*)d_ws + o;        o = align4(o + NBKT);
    float* dinv = (float*)d_ws + o;      o = align4(o + n);
    float* w3   = (float*)d_ws + o;      o = align4(o + 128);
    float* c3   = (float*)d_ws + o;      o = align4(o + 4);
    __half* Wt1 = (__half*)((int*)d_ws + o);     o = align4(o + 8192);
    __half* WtH = (__half*)((int*)d_ws + o);     o = align4(o + 8192);
    __half* bufA16 = (__half*)((int*)d_ws + o);  o = align4(o + (size_t)n * 64);
    __half* bufB16 = (__half*)((int*)d_ws + o);  o = align4(o + (size_t)n * 64);
    float* ys = (float*)bufB16;  // aliases bufB16 (h1s consumed by gemm2 first)

    const int B = (n + 255) / 256;
    const int GG = (n + 63) / 64;
    const int GA = (int)(((size_t)n * 32 + 255) / 256);

    // 1: histH || prep_w
    mega1<<<NB + 2, 256, 0, stream>>>(dst, hist, E, NBKT, NB,
                                      W1, Wh, W2, b2, Wo, bo, Wt1, WtH, w3, c3);
    // 2: per-bin prefix scan
    scanA<<<(NBKT * 64 + 255) / 256, 256, 0, stream>>>(hist, binsum, NBKT, NB);
    // 3: scatter || gemm1 (g1 = fp16(x@W1), unscaled)
    mega3<<<NB + GG, 256, 0, stream>>>(src, dst, hist, tmp, E, NBKT, NB,
                                       x, Wt1, bufA16, n);
    // 4: bucket compaction -> rowbeg/rowend/srcidx/dinv
    bucket_csr<<<NBKT, 256, 0, stream>>>(tmp, binsum, rowbeg, rowend, srcidx, dinv, n);
    // 5: layer-1 agg (per-edge dinv), h1s = di*relu(...) fp16
    agg_csr<0, 1><<<GA, 256, 0, stream>>>(rowbeg, rowend, srcidx, dinv, bufA16, b1, w3, bufB16, n);
    // 6: g2 = h1s@Wh
    gemm2_k<<<GG, 256, 0, stream>>>(bufB16, WtH, bufA16, n);
    // 7: layer-2 agg + fused layer-3 dot -> ys
    agg_csr<1, 0><<<GA, 256, 0, stream>>>(rowbeg, rowend, srcidx, dinv, bufA16, bh, w3, ys, n);
    // 8: layer-3 scalar aggregation + constant
    agg_csr_scalar<<<B, 256, 0, stream>>>(rowbeg, rowend, srcidx, dinv, ys, c3, out, n);
}

// Round 14
// 208.384 us; speedup vs baseline: 1.3218x; 1.3218x over previous
//
#include <hip/hip_runtime.h>
#include <hip/hip_fp16.h>

// GCN: N=100000, E=1600000, F=H=128, D=64, O=1.
// R14: R12's DENSE CSR (exact binbase via scanK2, dense srcidx, CHUNK 8192,
//      R12 agg verbatim) + R13's clean launch packing only:
//      mega1 = histH || prep_w ; mega3 = scatterH || gemm1.  9 launches.
// R13's strided CSR (sparse srcidx) is reverted — prime suspect for the
// 61->84us agg regression (L2 working-set pollution).

#define CHUNK 8192
#define ASTR 136   // LDS stride in halves

using f16x8 = __attribute__((ext_vector_type(8))) _Float16;
using f32x4 = __attribute__((ext_vector_type(4))) float;

// ====== device bodies ======
__device__ __forceinline__ void hist_body(const int* __restrict__ dst,
                                          int* __restrict__ hist,
                                          int E, int NBKT, int NB, int blk) {
    __shared__ int bins[1024];
    for (int i = threadIdx.x; i < NBKT; i += 256) bins[i] = 0;
    __syncthreads();
    int beg = blk * CHUNK, end = min(E, beg + CHUNK);
    for (int e = beg + threadIdx.x; e < end; e += 256)
        atomicAdd(&bins[dst[e] >> 7], 1);
    __syncthreads();
    for (int i = threadIdx.x; i < NBKT; i += 256)
        hist[i * NB + blk] = bins[i];
}

__device__ __forceinline__ void prep_body(int which,
                                          const float* __restrict__ W1,
                                          const float* __restrict__ Wh,
                                          const float* __restrict__ W2,
                                          const float* __restrict__ b2,
                                          const float* __restrict__ Wo,
                                          const float* __restrict__ bo,
                                          __half* __restrict__ Wt1,
                                          __half* __restrict__ WtH,
                                          float* __restrict__ w3,
                                          float* __restrict__ c3) {
    const float* W = which ? Wh : W1;
    __half* Wt = which ? WtH : Wt1;
    for (int i = threadIdx.x; i < 16384; i += 256) {
        int c = i >> 7, k = i & 127;
        Wt[c * 128 + k] = __float2half(W[k * 128 + c]);
    }
    if (which == 0 && threadIdx.x < 128) {
        int j = threadIdx.x;
        float s = 0.f;
        for (int d = 0; d < 64; ++d) s += W2[j * 64 + d] * Wo[d];
        w3[j] = s;
        if (j == 0) {
            float c = 0.f;
            for (int d = 0; d < 64; ++d) c += b2[d] * Wo[d];
            *c3 = c + bo[0];
        }
    }
}

__device__ __forceinline__ void scatter_body(const int* __restrict__ src,
                                             const int* __restrict__ dst,
                                             const int* __restrict__ hist,
                                             const int* __restrict__ binbase,
                                             int* __restrict__ tmp,
                                             int E, int NBKT, int NB, int blk) {
    __shared__ int offs[1024];
    for (int i = threadIdx.x; i < NBKT; i += 256)
        offs[i] = hist[i * NB + blk] + binbase[i];
    __syncthreads();
    int beg = blk * CHUNK, end = min(E, beg + CHUNK);
    for (int e = beg + threadIdx.x; e < end; e += 256) {
        int d = dst[e];
        int pos = atomicAdd(&offs[d >> 7], 1);
        tmp[pos] = ((d & 127) << 17) | src[e];
    }
}

// gemm body: Ch[n,128] = half(A[n,128] @ W), W^T fp16 table. No dinv.
template<typename AT>
__device__ __forceinline__ void gemm_body(const AT* __restrict__ A,
                                          const __half* __restrict__ Wt,
                                          __half* __restrict__ Ch, int n, int blk) {
    __shared__ _Float16 Al[64 * ASTR];
    __shared__ _Float16 Wl[128 * ASTR];
    const int tid = threadIdx.x;
    const int row0 = blk * 64;

#pragma unroll
    for (int i = 0; i < 8; ++i) {
        int idx = tid + 256 * i;
        int c = idx >> 4, q = idx & 15;
        uint4 v = *(const uint4*)(Wt + c * 128 + q * 8);
        *(uint4*)(&Wl[c * ASTR + q * 8]) = v;
    }
#pragma unroll
    for (int i = 0; i < 4; ++i) {
        int idx = tid + 256 * i;
        int r = idx >> 4, q = idx & 15;
        int row = row0 + r;
        uint4 u;
        if constexpr (sizeof(AT) == 2) {
            u = (row < n) ? *(const uint4*)((const __half*)A + (size_t)row * 128 + q * 8)
                          : make_uint4(0u, 0u, 0u, 0u);
        } else {
            if (row < n) {
                const float* ap = (const float*)A + (size_t)row * 128 + q * 8;
                float4 v0 = *(const float4*)ap;
                float4 v1 = *(const float4*)(ap + 4);
                __half2 p0 = __floats2half2_rn(v0.x, v0.y);
                __half2 p1 = __floats2half2_rn(v0.z, v0.w);
                __half2 p2 = __floats2half2_rn(v1.x, v1.y);
                __half2 p3 = __floats2half2_rn(v1.z, v1.w);
                u.x = *(unsigned*)&p0; u.y = *(unsigned*)&p1;
                u.z = *(unsigned*)&p2; u.w = *(unsigned*)&p3;
            } else u = make_uint4(0u, 0u, 0u, 0u);
        }
        *(uint4*)(&Al[r * ASTR + q * 8]) = u;
    }
    __syncthreads();

    const int wave = tid >> 6, lane = tid & 63;
    const int wr = (wave >> 1) * 32;
    const int wc = (wave & 1) * 64;
    const int l = lane & 15, g = lane >> 4;

    f32x4 acc[2][4];
#pragma unroll
    for (int i = 0; i < 2; ++i)
#pragma unroll
        for (int j = 0; j < 4; ++j) acc[i][j] = (f32x4){0.f, 0.f, 0.f, 0.f};

#pragma unroll
    for (int kk = 0; kk < 128; kk += 32) {
        int ko = kk + g * 8;
        f16x8 a0 = *(const f16x8*)(&Al[(wr + l) * ASTR + ko]);
        f16x8 a1 = *(const f16x8*)(&Al[(wr + 16 + l) * ASTR + ko]);
        f16x8 b0 = *(const f16x8*)(&Wl[(wc + l) * ASTR + ko]);
        f16x8 b1 = *(const f16x8*)(&Wl[(wc + 16 + l) * ASTR + ko]);
        f16x8 b2 = *(const f16x8*)(&Wl[(wc + 32 + l) * ASTR + ko]);
        f16x8 b3 = *(const f16x8*)(&Wl[(wc + 48 + l) * ASTR + ko]);
        acc[0][0] = __builtin_amdgcn_mfma_f32_16x16x32_f16(a0, b0, acc[0][0], 0, 0, 0);
        acc[0][1] = __builtin_amdgcn_mfma_f32_16x16x32_f16(a0, b1, acc[0][1], 0, 0, 0);
        acc[0][2] = __builtin_amdgcn_mfma_f32_16x16x32_f16(a0, b2, acc[0][2], 0, 0, 0);
        acc[0][3] = __builtin_amdgcn_mfma_f32_16x16x32_f16(a0, b3, acc[0][3], 0, 0, 0);
        acc[1][0] = __builtin_amdgcn_mfma_f32_16x16x32_f16(a1, b0, acc[1][0], 0, 0, 0);
        acc[1][1] = __builtin_amdgcn_mfma_f32_16x16x32_f16(a1, b1, acc[1][1], 0, 0, 0);
        acc[1][2] = __builtin_amdgcn_mfma_f32_16x16x32_f16(a1, b2, acc[1][2], 0, 0, 0);
        acc[1][3] = __builtin_amdgcn_mfma_f32_16x16x32_f16(a1, b3, acc[1][3], 0, 0, 0);
    }

    // D layout (m89-verified): col = lane&15, row = (lane>>4)*4 + reg
#pragma unroll
    for (int rt = 0; rt < 2; ++rt) {
#pragma unroll
        for (int j = 0; j < 4; ++j) {
            int row = row0 + wr + rt * 16 + g * 4 + j;
            if (row < n) {
#pragma unroll
                for (int ct = 0; ct < 4; ++ct)
                    Ch[(size_t)row * 128 + wc + ct * 16 + l] =
                        __float2half(acc[rt][ct][j]);
            }
        }
    }
}

// ====== fused launches ======
__global__ __launch_bounds__(256) void mega1(const int* __restrict__ dst,
                                             int* __restrict__ hist,
                                             int E, int NBKT, int NB,
                                             const float* __restrict__ W1,
                                             const float* __restrict__ Wh,
                                             const float* __restrict__ W2,
                                             const float* __restrict__ b2,
                                             const float* __restrict__ Wo,
                                             const float* __restrict__ bo,
                                             __half* __restrict__ Wt1,
                                             __half* __restrict__ WtH,
                                             float* __restrict__ w3,
                                             float* __restrict__ c3) {
    if ((int)blockIdx.x < NB)
        hist_body(dst, hist, E, NBKT, NB, blockIdx.x);
    else
        prep_body(blockIdx.x - NB, W1, Wh, W2, b2, Wo, bo, Wt1, WtH, w3, c3);
}

__global__ __launch_bounds__(256) void mega3(const int* __restrict__ src,
                                             const int* __restrict__ dst,
                                             const int* __restrict__ hist,
                                             const int* __restrict__ binbase,
                                             int* __restrict__ tmp,
                                             int E, int NBKT, int NB,
                                             const float* __restrict__ x,
                                             const __half* __restrict__ Wt1,
                                             __half* __restrict__ g1, int n) {
    if ((int)blockIdx.x < NB)
        scatter_body(src, dst, hist, binbase, tmp, E, NBKT, NB, blockIdx.x);
    else
        gemm_body<float>(x, Wt1, g1, n, blockIdx.x - NB);
}

__global__ __launch_bounds__(256) void gemm2_k(const __half* __restrict__ A,
                                               const __half* __restrict__ Wt,
                                               __half* __restrict__ Ch, int n) {
    gemm_body<__half>(A, Wt, Ch, n, blockIdx.x);
}

// ================= CSR build (dense, R12 semantics) =================
__global__ __launch_bounds__(256) void scanA(int* __restrict__ hist, int* __restrict__ binsum,
                                             int NBKT, int NB) {
    int wave = (int)((blockIdx.x * (size_t)blockDim.x + threadIdx.x) >> 6);
    if (wave >= NBKT) return;
    int lane = threadIdx.x & 63;
    int* row = hist + (size_t)wave * NB;
    int running = 0;
    for (int b0 = 0; b0 < NB; b0 += 64) {
        int idx = b0 + lane;
        int v = (idx < NB) ? row[idx] : 0;
        int s = v;
#pragma unroll
        for (int off = 1; off < 64; off <<= 1) {
            int u = __shfl_up(s, off, 64);
            if (lane >= off) s += u;
        }
        if (idx < NB) row[idx] = running + s - v;
        running += __shfl(s, 63, 64);
    }
    if (lane == 0) binsum[wave] = running;
}

__global__ void scanK2(const int* __restrict__ binsum, int* __restrict__ binbase,
                       int NBKT, int E) {
    __shared__ int s[1024];
    int t = threadIdx.x;
    int v = (t < NBKT) ? binsum[t] : 0;
    s[t] = v;
    __syncthreads();
    for (int off = 1; off < 1024; off <<= 1) {
        int u = (t >= off) ? s[t - off] : 0;
        __syncthreads();
        s[t] += u;
        __syncthreads();
    }
    if (t < NBKT) binbase[t] = s[t] - v;
    if (t == 0) binbase[NBKT] = E;
}

#define EBUF 2688
__global__ __launch_bounds__(256) void bucket_csr(const int* __restrict__ tmp,
                                                  const int* __restrict__ binbase,
                                                  int* __restrict__ rowptr,
                                                  int* __restrict__ srcidx,
                                                  float* __restrict__ dinv,
                                                  int n) {
    __shared__ int cnt[128], sc[128], cnt2[128];
    __shared__ int ebuf[EBUF];
    int b = blockIdx.x;
    int bstart = binbase[b], bend = binbase[b + 1];
    int cntE = bend - bstart;
    bool fit = (cntE <= EBUF);
    if (threadIdx.x < 128) cnt[threadIdx.x] = 0;
    __syncthreads();
    for (int e = threadIdx.x; e < cntE; e += 256) {
        int p = tmp[bstart + e];
        if (fit) ebuf[e] = p;
        atomicAdd(&cnt[p >> 17], 1);
    }
    __syncthreads();
    if (threadIdx.x < 128) sc[threadIdx.x] = cnt[threadIdx.x];
    __syncthreads();
    for (int off = 1; off < 128; off <<= 1) {
        int u = 0;
        if (threadIdx.x < 128 && threadIdx.x >= off) u = sc[threadIdx.x - off];
        __syncthreads();
        if (threadIdx.x < 128) sc[threadIdx.x] += u;
        __syncthreads();
    }
    if (threadIdx.x < 128) {
        int excl = sc[threadIdx.x] - cnt[threadIdx.x];
        cnt2[threadIdx.x] = excl;
        int id = b * 128 + threadIdx.x;
        if (id <= n) rowptr[id] = bstart + excl;
        if (id < n) dinv[id] = rsqrtf((float)cnt[threadIdx.x] + 1.0f);
    }
    __syncthreads();
    for (int e = threadIdx.x; e < cntE; e += 256) {
        int p = fit ? ebuf[e] : tmp[bstart + e];
        int pos = bstart + atomicAdd(&cnt2[p >> 17], 1);
        srcidx[pos] = p & 0x1FFFF;
    }
}

// ====== CSR gather: half-wave per node, 2 streams, 4-edge pipeline ======
template<int MODE, int EDGE_DINV>
__global__ __launch_bounds__(256) void agg_csr(const int* __restrict__ rowptr,
                                               const int* __restrict__ srcidx,
                                               const float* __restrict__ dinv,
                                               const __half* __restrict__ Gh,
                                               const float* __restrict__ bias,
                                               const float* __restrict__ w3,
                                               void* __restrict__ outp, int n) {
    int node = (int)((blockIdx.x * (size_t)blockDim.x + threadIdx.x) >> 5);
    if (node >= n) return;
    const int lane = threadIdx.x & 63;
    const int l32 = lane & 31;
    const int strm = l32 >> 4;
    const int l = l32 & 15;
    const int co = l * 8;
    int beg = rowptr[node], end = rowptr[node + 1];
    float di = dinv[node];

    float4 aLo = make_float4(0.f, 0.f, 0.f, 0.f);
    float4 aHi = make_float4(0.f, 0.f, 0.f, 0.f);

#define ACCS(u, s)                                                          \
    {                                                                       \
        float2 f0 = __half22float2(*(const __half2*)&(u).x);                \
        float2 f1 = __half22float2(*(const __half2*)&(u).y);                \
        float2 f2 = __half22float2(*(const __half2*)&(u).z);                \
        float2 f3 = __half22float2(*(const __half2*)&(u).w);                \
        aLo.x = fmaf(f0.x, s, aLo.x); aLo.y = fmaf(f0.y, s, aLo.y);         \
        aLo.z = fmaf(f1.x, s, aLo.z); aLo.w = fmaf(f1.y, s, aLo.w);         \
        aHi.x = fmaf(f2.x, s, aHi.x); aHi.y = fmaf(f2.y, s, aHi.y);         \
        aHi.z = fmaf(f3.x, s, aHi.z); aHi.w = fmaf(f3.y, s, aHi.w);         \
    }

    if (strm == 0) {  // self-loop term
        uint4 u = *(const uint4*)(Gh + (size_t)node * 128 + co);
        float sf = EDGE_DINV ? di : 1.0f;
        ACCS(u, sf);
    }

    int e = beg + strm;
    for (; e + 6 < end; e += 8) {
        int s0 = srcidx[e], s1 = srcidx[e + 2], s2 = srcidx[e + 4], s3 = srcidx[e + 6];
        float d0 = 1.f, d1 = 1.f, d2 = 1.f, d3 = 1.f;
        if (EDGE_DINV) { d0 = dinv[s0]; d1 = dinv[s1]; d2 = dinv[s2]; d3 = dinv[s3]; }
        uint4 u0 = *(const uint4*)(Gh + (size_t)s0 * 128 + co);
        uint4 u1 = *(const uint4*)(Gh + (size_t)s1 * 128 + co);
        uint4 u2 = *(const uint4*)(Gh + (size_t)s2 * 128 + co);
        uint4 u3 = *(const uint4*)(Gh + (size_t)s3 * 128 + co);
        ACCS(u0, d0);
        ACCS(u1, d1);
        ACCS(u2, d2);
        ACCS(u3, d3);
    }
    for (; e < end; e += 2) {
        int s0 = srcidx[e];
        float d0 = EDGE_DINV ? dinv[s0] : 1.0f;
        uint4 u0 = *(const uint4*)(Gh + (size_t)s0 * 128 + co);
        ACCS(u0, d0);
    }
#undef ACCS

    aLo.x += __shfl_xor(aLo.x, 16, 64); aLo.y += __shfl_xor(aLo.y, 16, 64);
    aLo.z += __shfl_xor(aLo.z, 16, 64); aLo.w += __shfl_xor(aLo.w, 16, 64);
    aHi.x += __shfl_xor(aHi.x, 16, 64); aHi.y += __shfl_xor(aHi.y, 16, 64);
    aHi.z += __shfl_xor(aHi.z, 16, 64); aHi.w += __shfl_xor(aHi.w, 16, 64);

    float4 b0 = *(const float4*)(bias + co);
    float4 b1 = *(const float4*)(bias + co + 4);
    float o0 = fmaxf(di * aLo.x + b0.x, 0.f);
    float o1 = fmaxf(di * aLo.y + b0.y, 0.f);
    float o2 = fmaxf(di * aLo.z + b0.z, 0.f);
    float o3 = fmaxf(di * aLo.w + b0.w, 0.f);
    float o4 = fmaxf(di * aHi.x + b1.x, 0.f);
    float o5 = fmaxf(di * aHi.y + b1.y, 0.f);
    float o6 = fmaxf(di * aHi.z + b1.z, 0.f);
    float o7 = fmaxf(di * aHi.w + b1.w, 0.f);

    if constexpr (MODE == 0) {
        if (strm == 0) {
            // h1s = di * h1 (pre-scaled so gemm2 needs no dinv)
            __half2 p0 = __floats2half2_rn(di * o0, di * o1);
            __half2 p1 = __floats2half2_rn(di * o2, di * o3);
            __half2 p2 = __floats2half2_rn(di * o4, di * o5);
            __half2 p3 = __floats2half2_rn(di * o6, di * o7);
            uint4 u;
            u.x = *(unsigned*)&p0; u.y = *(unsigned*)&p1;
            u.z = *(unsigned*)&p2; u.w = *(unsigned*)&p3;
            *(uint4*)((__half*)outp + (size_t)node * 128 + co) = u;
        }
    } else {
        float4 w0 = *(const float4*)(w3 + co);
        float4 w1 = *(const float4*)(w3 + co + 4);
        float v = o0 * w0.x + o1 * w0.y + o2 * w0.z + o3 * w0.w
                + o4 * w1.x + o5 * w1.y + o6 * w1.z + o7 * w1.w;
        v += __shfl_xor(v, 1, 64);
        v += __shfl_xor(v, 2, 64);
        v += __shfl_xor(v, 4, 64);
        v += __shfl_xor(v, 8, 64);
        if (l32 == 0) ((float*)outp)[node] = di * v;
    }
}

// ---- scalar CSR gather for final output ----
__global__ void agg_csr_scalar(const int* __restrict__ rowptr, const int* __restrict__ srcidx,
                               const float* __restrict__ dinv, const float* __restrict__ ys,
                               const float* __restrict__ c3, float* __restrict__ out, int n) {
    int i = blockIdx.x * blockDim.x + threadIdx.x;
    if (i >= n) return;
    int beg = rowptr[i], end = rowptr[i + 1];
    float acc = ys[i];
    int e = beg;
    for (; e + 3 < end; e += 4) {
        acc += ys[srcidx[e]] + ys[srcidx[e + 1]] + ys[srcidx[e + 2]] + ys[srcidx[e + 3]];
    }
    for (; e < end; ++e) acc += ys[srcidx[e]];
    out[i] = dinv[i] * acc + c3[0];
}

static inline size_t align4(size_t x) { return (x + 3) & ~(size_t)3; }

extern "C" void kernel_launch(void* const* d_in, const int* in_sizes, int n_in,
                              void* d_out, int out_size, void* d_ws, size_t ws_size,
                              hipStream_t stream) {
    const float* x  = (const float*)d_in[0];
    const int* ei   = (const int*)d_in[1];
    const float* W1 = (const float*)d_in[2];
    const float* b1 = (const float*)d_in[3];
    const float* Wh = (const float*)d_in[4];
    const float* bh = (const float*)d_in[5];
    const float* W2 = (const float*)d_in[6];
    const float* b2 = (const float*)d_in[7];
    const float* Wo = (const float*)d_in[8];
    const float* bo = (const float*)d_in[9];
    float* out = (float*)d_out;

    const int n = in_sizes[0] / 128;
    const int E = in_sizes[1] / 2;
    const int* src = ei;
    const int* dst = ei + E;

    const int NB = (E + CHUNK - 1) / CHUNK;
    const int NBKT = (n >> 7) + 1;

    size_t o = 0;
    int* rowptr = (int*)d_ws + o;        o = align4(o + n + 1);
    int* srcidx = (int*)d_ws + o;        o = align4(o + E);
    int* tmp    = (int*)d_ws + o;        o = align4(o + E);
    int* hist   = (int*)d_ws + o;        o = align4(o + (size_t)NBKT * NB);
    int* binsum = (int*)d_ws + o;        o = align4(o + NBKT);
    int* binbase= (int*)d_ws + o;        o = align4(o + NBKT + 1);
    float* dinv = (float*)d_ws + o;      o = align4(o + n);
    float* w3   = (float*)d_ws + o;      o = align4(o + 128);
    float* c3   = (float*)d_ws + o;      o = align4(o + 4);
    __half* Wt1 = (__half*)((int*)d_ws + o);     o = align4(o + 8192);
    __half* WtH = (__half*)((int*)d_ws + o);     o = align4(o + 8192);
    __half* bufA16 = (__half*)((int*)d_ws + o);  o = align4(o + (size_t)n * 64);
    __half* bufB16 = (__half*)((int*)d_ws + o);  o = align4(o + (size_t)n * 64);
    float* ys = (float*)bufB16;  // aliases bufB16 (h1s consumed by gemm2 first)

    const int B = (n + 255) / 256;
    const int GG = (n + 63) / 64;
    const int GA = (int)(((size_t)n * 32 + 255) / 256);

    // 1: histH || prep_w
    mega1<<<NB + 2, 256, 0, stream>>>(dst, hist, E, NBKT, NB,
                                      W1, Wh, W2, b2, Wo, bo, Wt1, WtH, w3, c3);
    // 2: per-bin prefix scan
    scanA<<<(NBKT * 64 + 255) / 256, 256, 0, stream>>>(hist, binsum, NBKT, NB);
    // 3: exact bucket bases
    scanK2<<<1, 1024, 0, stream>>>(binsum, binbase, NBKT, E);
    // 4: scatter || gemm1 (g1 = fp16(x@W1), unscaled)
    mega3<<<NB + GG, 256, 0, stream>>>(src, dst, hist, binbase, tmp, E, NBKT, NB,
                                       x, Wt1, bufA16, n);
    // 5: bucket compaction -> rowptr/srcidx/dinv (dense CSR)
    bucket_csr<<<NBKT, 256, 0, stream>>>(tmp, binbase, rowptr, srcidx, dinv, n);
    // 6: layer-1 agg (per-edge dinv), h1s = di*relu(...) fp16
    agg_csr<0, 1><<<GA, 256, 0, stream>>>(rowptr, srcidx, dinv, bufA16, b1, w3, bufB16, n);
    // 7: g2 = h1s@Wh
    gemm2_k<<<GG, 256, 0, stream>>>(bufB16, WtH, bufA16, n);
    // 8: layer-2 agg + fused layer-3 dot -> ys
    agg_csr<1, 0><<<GA, 256, 0, stream>>>(rowptr, srcidx, dinv, bufA16, bh, w3, ys, n);
    // 9: layer-3 scalar aggregation + constant
    agg_csr_scalar<<<B, 256, 0, stream>>>(rowptr, srcidx, dinv, ys, c3, out, n);
}